// Round 3
// baseline (4585.036 us; speedup 1.0000x reference)
//
#include <hip/hip_runtime.h>
#include <stdint.h>

#define B_ 2
#define N_ 4096
#define D_ 256
#define H_ 8
#define DH_ 64
#define INNER_ 512
#define NBH 16
#define PAD 72
#define FPAD 80   // byte stride for fp8 LDS tiles (20 words: conflict-free, 8B-aligned)

typedef unsigned short ushort_t;
typedef __attribute__((ext_vector_type(8))) short short8;
typedef __attribute__((ext_vector_type(4))) float float4v;
typedef __attribute__((ext_vector_type(4))) unsigned short ushort4v;
typedef __attribute__((ext_vector_type(16))) unsigned char uchar16v;

__device__ __forceinline__ ushort_t f2bf(float f) {
    union { float f; unsigned int u; } v; v.f = f;
    unsigned int r = v.u + 0x7FFFu + ((v.u >> 16) & 1u);
    return (ushort_t)(r >> 16);
}

// fp8 e4m3 encode (RNE), positive normal values only (E = exp(..) in ~[0.1,8])
__device__ __forceinline__ unsigned char f2fp8(float f) {
    union { float f; unsigned int u; } v; v.f = f;
    unsigned int u = v.u + 0x7FFFFu + ((v.u >> 20) & 1u);
    return (unsigned char)(((u >> 20) & 0x7FF) - 960);  // ((e-120)<<3)|m
}

// full signed fp8 e4m3 encode with subnormal + clamp handling (for t values)
__device__ __forceinline__ unsigned char f2fp8s(float f) {
    union { float f; unsigned int u; } v; v.f = f;
    unsigned int s = (v.u >> 24) & 0x80u;
    v.u &= 0x7FFFFFFFu;
    float a = v.f;
    if (a >= 448.f) return (unsigned char)(s | 0x7E);       // clamp to max
    if (a < 0.015625f) {                                    // subnormal (<2^-6)
        int m = (int)(a * 512.f + 0.5f);
        return (unsigned char)(s | (unsigned)m);
    }
    unsigned int u = v.u + 0x7FFFFu + ((v.u >> 20) & 1u);
    return (unsigned char)(s | (((u >> 20) & 0x7FF) - 960));
}

// ---------------- prep: bf16 conversions + weight transposes ----------------
__global__ __launch_bounds__(256) void prep_kernel(
    const float* __restrict__ x, const float* __restrict__ Wq,
    const float* __restrict__ Wk, const float* __restrict__ Wv,
    const float* __restrict__ Wo,
    ushort_t* __restrict__ xb, ushort_t* __restrict__ WqkvT,
    ushort_t* __restrict__ WoT) {
    int idx = blockIdx.x * 256 + threadIdx.x;
    const int total_x = B_ * N_ * D_;
    const int total_wqkv = 3 * INNER_ * D_;
    const int total_wo = D_ * INNER_;
    if (idx < total_x) { xb[idx] = f2bf(x[idx]); return; }
    idx -= total_x;
    if (idx < total_wqkv) {
        int n = idx >> 8, k = idx & 255;
        int which = n >> 9, nn = n & 511;
        const float* W = (which == 0) ? Wq : ((which == 1) ? Wk : Wv);
        WqkvT[idx] = f2bf(W[k * INNER_ + nn]);
        return;
    }
    idx -= total_wqkv;
    if (idx < total_wo) {
        int c = idx >> 9, k = idx & 511;
        WoT[idx] = f2bf(Wo[k * D_ + c]);
    }
}

// ---------------- fused QKV projection GEMM: [8192,256] x [256,1536] --------
__global__ __launch_bounds__(256) void proj_gemm(
    const ushort_t* __restrict__ xb, const ushort_t* __restrict__ WqkvT,
    ushort_t* __restrict__ Qb, ushort_t* __restrict__ Kb,
    float* __restrict__ Vf) {
    __shared__ ushort_t As[128][PAD];
    __shared__ ushort_t Bs[128][PAD];
    int bid = blockIdx.x;
    int tileN = bid % 12, tileM = bid / 12;
    int tid = threadIdx.x;
    int w = tid >> 6, lane = tid & 63, q = lane >> 4, r = lane & 15;
    int wr = (w & 1) * 64, wc = (w >> 1) * 64;
    float4v acc[4][4];
    for (int i = 0; i < 4; i++)
        for (int j = 0; j < 4; j++)
            for (int e = 0; e < 4; e++) acc[i][j][e] = 0.f;

    for (int k0 = 0; k0 < 256; k0 += 64) {
        for (int it = 0; it < 4; it++) {
            int idx = tid + it * 256;
            int row = idx >> 3, kc = (idx & 7) * 8;
            *(short8*)&As[row][kc] =
                *(const short8*)&xb[(size_t)(tileM * 128 + row) * 256 + k0 + kc];
            *(short8*)&Bs[row][kc] =
                *(const short8*)&WqkvT[(size_t)(tileN * 128 + row) * 256 + k0 + kc];
        }
        __syncthreads();
        for (int kk = 0; kk < 64; kk += 32) {
            short8 a[4], b[4];
            for (int mi = 0; mi < 4; mi++)
                a[mi] = *(const short8*)&As[wr + mi * 16 + r][kk + q * 8];
            for (int ni = 0; ni < 4; ni++)
                b[ni] = *(const short8*)&Bs[wc + ni * 16 + r][kk + q * 8];
            for (int mi = 0; mi < 4; mi++)
                for (int ni = 0; ni < 4; ni++)
                    acc[mi][ni] = __builtin_amdgcn_mfma_f32_16x16x32_bf16(
                        a[mi], b[ni], acc[mi][ni], 0, 0, 0);
        }
        __syncthreads();
    }
    for (int mi = 0; mi < 4; mi++)
        for (int ni = 0; ni < 4; ni++)
            for (int reg = 0; reg < 4; reg++) {
                int grow = tileM * 128 + wr + mi * 16 + q * 4 + reg;
                int gcol = tileN * 128 + wc + ni * 16 + r;
                float v = acc[mi][ni][reg];
                int which = gcol >> 9, inner = gcol & 511;
                int h = inner >> 6, d = inner & 63;
                int b = grow >> 12, n = grow & 4095;
                size_t off = (((size_t)(b * H_ + h)) * N_ + n) * DH_ + d;
                if (which == 0) Qb[off] = f2bf(v);
                else if (which == 1) Kb[off] = f2bf(v);
                else Vf[off] = v;
            }
}

// ---------------- per-head LayerNorm + y init + transposed t0 (fp8) ---------
__global__ __launch_bounds__(256) void ln_kernel(
    const float* __restrict__ Vf, const float* __restrict__ gamma,
    const float* __restrict__ beta, const float* __restrict__ coeffs,
    unsigned char* __restrict__ t0T, float* __restrict__ y) {
    int tid = threadIdx.x;
    int wave = tid >> 6, lane = tid & 63;
    size_t row = (size_t)blockIdx.x * 4 + wave;   // bh*4096 + n
    int bh = (int)(row >> 12), n = (int)(row & 4095);
    int h = bh & 7;
    float v = Vf[row * 64 + lane];
    float s = v;
    for (int m = 32; m >= 1; m >>= 1) s += __shfl_xor(s, m, 64);
    float mu = s * (1.f / 64.f);
    float dv = v - mu;
    float s2 = dv * dv;
    for (int m = 32; m >= 1; m >>= 1) s2 += __shfl_xor(s2, m, 64);
    float var = s2 * (1.f / 64.f);
    float vln = dv * rsqrtf(var + 1e-5f) * gamma[lane] + beta[lane];
    float c0 = coeffs[h * 4 + 0];
    y[row * 64 + lane] = c0 * vln;
    t0T[((size_t)bh * 64 + lane) * 4096 + n] = f2fp8s(vln);
}

// ---------------- E = exp(Q K^T / 8), fp8 e4m3, per (b,h) in group ----------
__global__ __launch_bounds__(256) void s_kernel(
    const ushort_t* __restrict__ Qb, const ushort_t* __restrict__ Kb,
    unsigned char* __restrict__ E, int bh0) {
    __shared__ ushort_t As[128][PAD];
    __shared__ ushort_t Bs[128][PAD];
    int bid = blockIdx.x;
    int local = bid >> 10;
    int rem = bid & 1023;
    int ti = rem >> 5, tj = rem & 31;
    int bh = bh0 + local;
    const ushort_t* Q = Qb + (size_t)bh * N_ * 64;
    const ushort_t* K = Kb + (size_t)bh * N_ * 64;
    unsigned char* Eg = E + (size_t)local * N_ * N_;
    int tid = threadIdx.x, w = tid >> 6, lane = tid & 63, q = lane >> 4, r = lane & 15;
    int wr = (w & 1) * 64, wc = (w >> 1) * 64;
    float4v acc[4][4];
    for (int i = 0; i < 4; i++)
        for (int j = 0; j < 4; j++)
            for (int e = 0; e < 4; e++) acc[i][j][e] = 0.f;

    for (int it = 0; it < 4; it++) {
        int idx = tid + it * 256;
        int row = idx >> 3, kc = (idx & 7) * 8;
        *(short8*)&As[row][kc] = *(const short8*)&Q[(size_t)(ti * 128 + row) * 64 + kc];
        *(short8*)&Bs[row][kc] = *(const short8*)&K[(size_t)(tj * 128 + row) * 64 + kc];
    }
    __syncthreads();
    for (int kk = 0; kk < 64; kk += 32) {
        short8 a[4], b[4];
        for (int mi = 0; mi < 4; mi++)
            a[mi] = *(const short8*)&As[wr + mi * 16 + r][kk + q * 8];
        for (int ni = 0; ni < 4; ni++)
            b[ni] = *(const short8*)&Bs[wc + ni * 16 + r][kk + q * 8];
        for (int mi = 0; mi < 4; mi++)
            for (int ni = 0; ni < 4; ni++)
                acc[mi][ni] = __builtin_amdgcn_mfma_f32_16x16x32_bf16(
                    a[mi], b[ni], acc[mi][ni], 0, 0, 0);
    }
    for (int mi = 0; mi < 4; mi++)
        for (int ni = 0; ni < 4; ni++)
            for (int reg = 0; reg < 4; reg++) {
                int grow = ti * 128 + wr + mi * 16 + q * 4 + reg;
                int gcol = tj * 128 + wc + ni * 16 + r;
                Eg[(size_t)grow * 4096 + gcol] =
                    f2fp8(__expf(0.125f * acc[mi][ni][reg]));
            }
}

// ---------------- filter pass: t_out = (E t_in)/rowsum ; y += c_k t_out -----
// all-fp8 MFMA, 64-row tiles, depth-2 register prefetch pipeline
__global__ __launch_bounds__(256) void filter_kernel(
    const unsigned char* __restrict__ E, const unsigned char* __restrict__ tinT,
    unsigned char* __restrict__ toutT, float* __restrict__ y,
    const float* __restrict__ coeffs, int bh0, int kidx, int write_t) {
    __shared__ unsigned char Es[64][FPAD];
    __shared__ unsigned char Ts[64][FPAD];
    int bid = blockIdx.x;
    int local = bid >> 6;          // bh within group
    int ti = bid & 63;             // 64-row tile index
    int bh = bh0 + local;
    int h = bh & 7;
    float ck = coeffs[h * 4 + kidx];
    const unsigned char* Eg = E + (size_t)local * N_ * N_;
    const unsigned char* tin = tinT + (size_t)bh * 64 * N_;
    int tid = threadIdx.x, w = tid >> 6, lane = tid & 63, q = lane >> 4, r = lane & 15;

    int srow = tid >> 2, scol = (tid & 3) * 16;  // staging: 4 lanes per 64B row
    const unsigned char* Eptr = &Eg[(size_t)(ti * 64 + srow) * 4096 + scol];
    const unsigned char* Tptr = &tin[(size_t)srow * 4096 + scol];

    float4v acc[4], accs;
    for (int e = 0; e < 4; e++) accs[e] = 0.f;
    for (int j = 0; j < 4; j++)
        for (int e = 0; e < 4; e++) acc[j][e] = 0.f;
    const long bones = 0x3838383838383838L;  // 8x fp8(1.0)

    uchar16v ev[2], tv[2];
    ev[0] = *(const uchar16v*)(Eptr);       tv[0] = *(const uchar16v*)(Tptr);
    ev[1] = *(const uchar16v*)(Eptr + 64);  tv[1] = *(const uchar16v*)(Tptr + 64);

    for (int k0 = 0; k0 < 64; k0++) {
        int cur = k0 & 1;
        __syncthreads();   // previous iteration's LDS reads complete
        *(uchar16v*)&Es[srow][scol] = ev[cur];
        *(uchar16v*)&Ts[srow][scol] = tv[cur];
        __syncthreads();
        if (k0 + 2 < 64) {  // prefetch 2 iterations ahead
            ev[cur] = *(const uchar16v*)(Eptr + (size_t)(k0 + 2) * 64);
            tv[cur] = *(const uchar16v*)(Tptr + (size_t)(k0 + 2) * 64);
        }
        for (int kk = 0; kk < 64; kk += 32) {
            long a = *(const long*)&Es[w * 16 + r][kk + q * 8];
            long b[4];
            for (int ni = 0; ni < 4; ni++)
                b[ni] = *(const long*)&Ts[ni * 16 + r][kk + q * 8];
            for (int ni = 0; ni < 4; ni++)
                acc[ni] = __builtin_amdgcn_mfma_f32_16x16x32_fp8_fp8(
                    a, b[ni], acc[ni], 0, 0, 0);
            accs = __builtin_amdgcn_mfma_f32_16x16x32_fp8_fp8(a, bones, accs, 0, 0, 0);
        }
    }
    for (int reg = 0; reg < 4; reg++) {
        float inv = 1.f / accs[reg];
        int grow = ti * 64 + w * 16 + q * 4 + reg;
        for (int ni = 0; ni < 4; ni++) {
            int gcol = ni * 16 + r;  // d
            float tvv = acc[ni][reg] * inv;
            y[((size_t)bh * 4096 + grow) * 64 + gcol] += ck * tvv;
            if (write_t)
                toutT[((size_t)bh * 64 + gcol) * 4096 + grow] = f2fp8s(tvv);
        }
    }
}

// ---------------- output projection: merged[8192,512] x Wo[512,256] ---------
__global__ __launch_bounds__(256) void out_gemm(
    const float* __restrict__ y, const ushort_t* __restrict__ WoT,
    float* __restrict__ out) {
    __shared__ ushort_t As[128][PAD];
    __shared__ ushort_t Bs[64][PAD];
    int bid = blockIdx.x;
    int tileN = bid & 3, tileM = bid >> 2;
    int tid = threadIdx.x, w = tid >> 6, lane = tid & 63, q = lane >> 4, r = lane & 15;
    int wr = w * 32;
    float4v acc[2][4];
    for (int i = 0; i < 2; i++)
        for (int j = 0; j < 4; j++)
            for (int e = 0; e < 4; e++) acc[i][j][e] = 0.f;

    for (int k0 = 0; k0 < 512; k0 += 64) {
        int h = k0 >> 6;
        for (int it = 0; it < 8; it++) {
            int idx = tid + it * 256;
            int row = idx >> 4, kc = (idx & 15) * 4;
            int grow = tileM * 128 + row;
            int b = grow >> 12, n = grow & 4095;
            const float4* src =
                (const float4*)&y[(((size_t)(b * H_ + h)) * N_ + n) * 64 + kc];
            float4 v = *src;
            ushort4v pv;
            pv[0] = f2bf(v.x); pv[1] = f2bf(v.y); pv[2] = f2bf(v.z); pv[3] = f2bf(v.w);
            *(ushort4v*)&As[row][kc] = pv;
        }
        for (int it = 0; it < 2; it++) {
            int idx = tid + it * 256;
            int row = idx >> 3, kc = (idx & 7) * 8;
            *(short8*)&Bs[row][kc] =
                *(const short8*)&WoT[(size_t)(tileN * 64 + row) * 512 + k0 + kc];
        }
        __syncthreads();
        for (int kk = 0; kk < 64; kk += 32) {
            short8 a[2], b[4];
            a[0] = *(const short8*)&As[wr + r][kk + q * 8];
            a[1] = *(const short8*)&As[wr + 16 + r][kk + q * 8];
            for (int ni = 0; ni < 4; ni++)
                b[ni] = *(const short8*)&Bs[ni * 16 + r][kk + q * 8];
            for (int mi = 0; mi < 2; mi++)
                for (int ni = 0; ni < 4; ni++)
                    acc[mi][ni] = __builtin_amdgcn_mfma_f32_16x16x32_bf16(
                        a[mi], b[ni], acc[mi][ni], 0, 0, 0);
        }
        __syncthreads();
    }
    for (int mi = 0; mi < 2; mi++)
        for (int reg = 0; reg < 4; reg++) {
            int grow = tileM * 128 + wr + mi * 16 + q * 4 + reg;
            for (int ni = 0; ni < 4; ni++) {
                int gcol = tileN * 64 + ni * 16 + r;
                out[(size_t)grow * 256 + gcol] = acc[mi][ni][reg];
            }
        }
}

// ---------------------------------------------------------------------------
extern "C" void kernel_launch(void* const* d_in, const int* in_sizes, int n_in,
                              void* d_out, int out_size, void* d_ws, size_t ws_size,
                              hipStream_t stream) {
    const float* x      = (const float*)d_in[0];
    const float* Wq     = (const float*)d_in[1];
    const float* Wk     = (const float*)d_in[2];
    const float* Wv     = (const float*)d_in[3];
    const float* Wo     = (const float*)d_in[4];
    const float* gamma  = (const float*)d_in[5];
    const float* beta   = (const float*)d_in[6];
    const float* coeffs = (const float*)d_in[7];
    float* out = (float*)d_out;

    char* ws = (char*)d_ws;
    size_t off = 0;
    auto alloc = [&](size_t bytes) -> void* {
        void* p = ws + off;
        off += (bytes + 255) & ~(size_t)255;
        return p;
    };
    ushort_t* xb    = (ushort_t*)alloc((size_t)B_ * N_ * D_ * 2);
    ushort_t* WqkvT = (ushort_t*)alloc((size_t)3 * INNER_ * D_ * 2);
    ushort_t* WoT   = (ushort_t*)alloc((size_t)D_ * INNER_ * 2);
    ushort_t* Qb    = (ushort_t*)alloc((size_t)NBH * N_ * DH_ * 2);
    ushort_t* Kb    = (ushort_t*)alloc((size_t)NBH * N_ * DH_ * 2);
    float*    Vf    = (float*)alloc((size_t)NBH * N_ * DH_ * 4);
    unsigned char* t0T = (unsigned char*)alloc((size_t)NBH * DH_ * N_);
    unsigned char* t1T = (unsigned char*)alloc((size_t)NBH * DH_ * N_);
    unsigned char* t2T = (unsigned char*)alloc((size_t)NBH * DH_ * N_);
    float*    y     = (float*)alloc((size_t)NBH * N_ * DH_ * 4);

    const size_t E1 = (size_t)N_ * N_;  // 16.78 MB per (b,h) in fp8
    int nbh_g = NBH;
    while (nbh_g > 1 && off + (size_t)nbh_g * E1 > ws_size) nbh_g >>= 1;
    unsigned char* E = (unsigned char*)(ws + off);

    const int prep_total = B_ * N_ * D_ + 3 * INNER_ * D_ + D_ * INNER_;
    prep_kernel<<<(prep_total + 255) / 256, 256, 0, stream>>>(
        x, Wq, Wk, Wv, Wo, xb, WqkvT, WoT);
    proj_gemm<<<768, 256, 0, stream>>>(xb, WqkvT, Qb, Kb, Vf);
    ln_kernel<<<(NBH * N_) / 4, 256, 0, stream>>>(Vf, gamma, beta, coeffs, t0T, y);

    for (int bh0 = 0; bh0 < NBH; bh0 += nbh_g) {
        s_kernel<<<nbh_g * 1024, 256, 0, stream>>>(Qb, Kb, E, bh0);
        filter_kernel<<<nbh_g * 64, 256, 0, stream>>>(E, t0T, t1T, y, coeffs, bh0, 1, 1);
        filter_kernel<<<nbh_g * 64, 256, 0, stream>>>(E, t1T, t2T, y, coeffs, bh0, 2, 1);
        filter_kernel<<<nbh_g * 64, 256, 0, stream>>>(E, t2T, t1T, y, coeffs, bh0, 3, 0);
    }
    out_gemm<<<256, 256, 0, stream>>>(y, WoT, out);
}

// Round 4
// 633.244 us; speedup vs baseline: 7.2406x; 7.2406x over previous
//
#include <hip/hip_runtime.h>
#include <stdint.h>

#define B_ 2
#define N_ 4096
#define D_ 256
#define H_ 8
#define DH_ 64
#define INNER_ 512
#define NBH 16
#define PAD 72
#define SPLIT 2

typedef unsigned short ushort_t;
typedef __attribute__((ext_vector_type(8))) short short8;
typedef __attribute__((ext_vector_type(4))) float float4v;
typedef __attribute__((ext_vector_type(4))) unsigned short ushort4v;
typedef __attribute__((ext_vector_type(16))) unsigned char uchar16v;

__device__ __forceinline__ ushort_t f2bf(float f) {
    union { float f; unsigned int u; } v; v.f = f;
    unsigned int r = v.u + 0x7FFFu + ((v.u >> 16) & 1u);
    return (ushort_t)(r >> 16);
}
__device__ __forceinline__ float bf2f(ushort_t u) {
    union { unsigned int u; float f; } v; v.u = ((unsigned int)u) << 16;
    return v.f;
}
// fp8 e4m3 encode (RNE), positive normal values only (E = exp(..) small range)
__device__ __forceinline__ unsigned char f2fp8(float f) {
    union { float f; unsigned int u; } v; v.f = f;
    unsigned int u = v.u + 0x7FFFFu + ((v.u >> 20) & 1u);
    return (unsigned char)(((u >> 20) & 0x7FF) - 960);  // ((e-120)<<3)|m
}

// ---------------- prep: bf16 conversions + weight transposes ----------------
__global__ __launch_bounds__(256) void prep_kernel(
    const float* __restrict__ x, const float* __restrict__ Wq,
    const float* __restrict__ Wk, const float* __restrict__ Wv,
    const float* __restrict__ Wo,
    ushort_t* __restrict__ xb, ushort_t* __restrict__ WqkvT,
    ushort_t* __restrict__ WoT) {
    int idx = blockIdx.x * 256 + threadIdx.x;
    const int total_x = B_ * N_ * D_;
    const int total_wqkv = 3 * INNER_ * D_;
    const int total_wo = D_ * INNER_;
    if (idx < total_x) { xb[idx] = f2bf(x[idx]); return; }
    idx -= total_x;
    if (idx < total_wqkv) {
        int n = idx >> 8, k = idx & 255;
        int which = n >> 9, nn = n & 511;
        const float* W = (which == 0) ? Wq : ((which == 1) ? Wk : Wv);
        WqkvT[idx] = f2bf(W[k * INNER_ + nn]);
        return;
    }
    idx -= total_wqkv;
    if (idx < total_wo) {
        int c = idx >> 9, k = idx & 511;
        WoT[idx] = f2bf(Wo[k * D_ + c]);
    }
}

// ---------------- fused QKV projection GEMM: [8192,256] x [256,1536] --------
__global__ __launch_bounds__(256) void proj_gemm(
    const ushort_t* __restrict__ xb, const ushort_t* __restrict__ WqkvT,
    ushort_t* __restrict__ Qb, ushort_t* __restrict__ Kb,
    ushort_t* __restrict__ Vb) {
    __shared__ ushort_t As[128][PAD];
    __shared__ ushort_t Bs[128][PAD];
    int bid = blockIdx.x;
    int tileN = bid % 12, tileM = bid / 12;
    int tid = threadIdx.x;
    int w = tid >> 6, lane = tid & 63, q = lane >> 4, r = lane & 15;
    int wr = (w & 1) * 64, wc = (w >> 1) * 64;
    float4v acc[4][4];
    for (int i = 0; i < 4; i++)
        for (int j = 0; j < 4; j++)
            for (int e = 0; e < 4; e++) acc[i][j][e] = 0.f;

    for (int k0 = 0; k0 < 256; k0 += 64) {
        for (int it = 0; it < 4; it++) {
            int idx = tid + it * 256;
            int row = idx >> 3, kc = (idx & 7) * 8;
            *(short8*)&As[row][kc] =
                *(const short8*)&xb[(size_t)(tileM * 128 + row) * 256 + k0 + kc];
            *(short8*)&Bs[row][kc] =
                *(const short8*)&WqkvT[(size_t)(tileN * 128 + row) * 256 + k0 + kc];
        }
        __syncthreads();
        for (int kk = 0; kk < 64; kk += 32) {
            short8 a[4], b[4];
            for (int mi = 0; mi < 4; mi++)
                a[mi] = *(const short8*)&As[wr + mi * 16 + r][kk + q * 8];
            for (int ni = 0; ni < 4; ni++)
                b[ni] = *(const short8*)&Bs[wc + ni * 16 + r][kk + q * 8];
            for (int mi = 0; mi < 4; mi++)
                for (int ni = 0; ni < 4; ni++)
                    acc[mi][ni] = __builtin_amdgcn_mfma_f32_16x16x32_bf16(
                        a[mi], b[ni], acc[mi][ni], 0, 0, 0);
        }
        __syncthreads();
    }
    for (int mi = 0; mi < 4; mi++)
        for (int ni = 0; ni < 4; ni++)
            for (int reg = 0; reg < 4; reg++) {
                int grow = tileM * 128 + wr + mi * 16 + q * 4 + reg;
                int gcol = tileN * 128 + wc + ni * 16 + r;
                float v = acc[mi][ni][reg];
                int which = gcol >> 9, inner = gcol & 511;
                int h = inner >> 6, d = inner & 63;
                int b = grow >> 12, n = grow & 4095;
                size_t off = (((size_t)(b * H_ + h)) * N_ + n) * DH_ + d;
                if (which == 0) Qb[off] = f2bf(v);
                else if (which == 1) Kb[off] = f2bf(v);
                else Vb[off] = f2bf(v);
            }
}

// ---------------- per-head LayerNorm + y init + transposed t0 ---------------
__global__ __launch_bounds__(256) void ln_kernel(
    const ushort_t* __restrict__ Vb, const float* __restrict__ gamma,
    const float* __restrict__ beta, const float* __restrict__ coeffs,
    ushort_t* __restrict__ t0T, float* __restrict__ y) {
    int tid = threadIdx.x;
    int wave = tid >> 6, lane = tid & 63;
    size_t row = (size_t)blockIdx.x * 4 + wave;   // bh*4096 + n
    int bh = (int)(row >> 12), n = (int)(row & 4095);
    int h = bh & 7;
    float v = bf2f(Vb[row * 64 + lane]);
    float s = v;
    for (int m = 32; m >= 1; m >>= 1) s += __shfl_xor(s, m, 64);
    float mu = s * (1.f / 64.f);
    float dv = v - mu;
    float s2 = dv * dv;
    for (int m = 32; m >= 1; m >>= 1) s2 += __shfl_xor(s2, m, 64);
    float var = s2 * (1.f / 64.f);
    float vln = dv * rsqrtf(var + 1e-5f) * gamma[lane] + beta[lane];
    float c0 = coeffs[h * 4 + 0];
    y[row * 64 + lane] = c0 * vln;
    t0T[((size_t)bh * 64 + lane) * 4096 + n] = f2bf(vln);
}

// ---------------- E = exp(Q K^T / 8), fp8 e4m3, per (b,h) in group ----------
__global__ __launch_bounds__(256) void s_kernel(
    const ushort_t* __restrict__ Qb, const ushort_t* __restrict__ Kb,
    unsigned char* __restrict__ E, int bh0) {
    __shared__ ushort_t As[128][PAD];
    __shared__ ushort_t Bs[128][PAD];
    int bid = blockIdx.x;
    int local = bid >> 10;
    int rem = bid & 1023;
    int ti = rem >> 5, tj = rem & 31;
    int bh = bh0 + local;
    const ushort_t* Q = Qb + (size_t)bh * N_ * 64;
    const ushort_t* K = Kb + (size_t)bh * N_ * 64;
    unsigned char* Eg = E + (size_t)local * N_ * N_;
    int tid = threadIdx.x, w = tid >> 6, lane = tid & 63, q = lane >> 4, r = lane & 15;
    int wr = (w & 1) * 64, wc = (w >> 1) * 64;
    float4v acc[4][4];
    for (int i = 0; i < 4; i++)
        for (int j = 0; j < 4; j++)
            for (int e = 0; e < 4; e++) acc[i][j][e] = 0.f;

    for (int it = 0; it < 4; it++) {
        int idx = tid + it * 256;
        int row = idx >> 3, kc = (idx & 7) * 8;
        *(short8*)&As[row][kc] = *(const short8*)&Q[(size_t)(ti * 128 + row) * 64 + kc];
        *(short8*)&Bs[row][kc] = *(const short8*)&K[(size_t)(tj * 128 + row) * 64 + kc];
    }
    __syncthreads();
    for (int kk = 0; kk < 64; kk += 32) {
        short8 a[4], b[4];
        for (int mi = 0; mi < 4; mi++)
            a[mi] = *(const short8*)&As[wr + mi * 16 + r][kk + q * 8];
        for (int ni = 0; ni < 4; ni++)
            b[ni] = *(const short8*)&Bs[wc + ni * 16 + r][kk + q * 8];
        for (int mi = 0; mi < 4; mi++)
            for (int ni = 0; ni < 4; ni++)
                acc[mi][ni] = __builtin_amdgcn_mfma_f32_16x16x32_bf16(
                    a[mi], b[ni], acc[mi][ni], 0, 0, 0);
    }
    for (int mi = 0; mi < 4; mi++)
        for (int ni = 0; ni < 4; ni++)
            for (int reg = 0; reg < 4; reg++) {
                int grow = ti * 128 + wr + mi * 16 + q * 4 + reg;
                int gcol = tj * 128 + wc + ni * 16 + r;
                Eg[(size_t)grow * 4096 + gcol] =
                    f2fp8(__expf(0.125f * acc[mi][ni][reg]));
            }
}

// ---------------- filter partial: u += E[:,chunk] t[chunk], s += rowsum -----
// R2 structure (fp8 E decoded to bf16 in staging, bf16 MFMA), K split across
// SPLIT blocks for occupancy; partials accumulated via global f32 atomics.
__global__ __launch_bounds__(256) void filter_p(
    const unsigned char* __restrict__ E, const ushort_t* __restrict__ tinT,
    float* __restrict__ u, float* __restrict__ s) {
    __shared__ ushort_t Es[64][PAD];
    __shared__ ushort_t Ts[64][PAD];
    int bid = blockIdx.x;
    int local = bid >> 7;              // bh within group
    int rem = bid & 127;
    int ti = rem >> 1;                 // 64-row tile index
    int half = rem & 1;                // K chunk
    const unsigned char* Eg = E + (size_t)local * N_ * N_;
    const ushort_t* tin = tinT + ((size_t)local + ((size_t)local / H_) * 0) * 0; // placeholder
    (void)tin;
    int tid = threadIdx.x, w = tid >> 6, lane = tid & 63, q = lane >> 4, r = lane & 15;
    float4v acc[4], accs;
    for (int e = 0; e < 4; e++) accs[e] = 0.f;
    for (int j = 0; j < 4; j++)
        for (int e = 0; e < 4; e++) acc[j][e] = 0.f;
    const short one_bf = (short)0x3F80;
    short8 bones = { one_bf, one_bf, one_bf, one_bf, one_bf, one_bf, one_bf, one_bf };

    int erow = tid >> 2, ejc = (tid & 3) * 16;   // E staging: 4 lanes per 64B row
    const ushort_t* tsl = tinT;  // tinT already offset per-bh by caller-computed base below

    int kbeg = half * (N_ / SPLIT), kend = kbeg + N_ / SPLIT;
    for (int k0 = kbeg; k0 < kend; k0 += 64) {
        // stage E tile 64x64 fp8 -> bf16 LDS
        uchar16v ev = *(const uchar16v*)&Eg[((size_t)(ti * 64 + erow)) * 4096 + k0 + ejc];
        short8 lo, hi;
        for (int e = 0; e < 8; e++) {
            lo[e] = (short)(((ushort_t)ev[e] << 4) + 0x3C00);
            hi[e] = (short)(((ushort_t)ev[e + 8] << 4) + 0x3C00);
        }
        *(short8*)&Es[erow][ejc] = lo;
        *(short8*)&Es[erow][ejc + 8] = hi;
        // stage tin tile 64(d) x 64(j)
        for (int it = 0; it < 2; it++) {
            int idx = tid + it * 256;
            int row = idx >> 3, jc = (idx & 7) * 8;
            *(short8*)&Ts[row][jc] = *(const short8*)&tsl[(size_t)row * 4096 + k0 + jc];
        }
        __syncthreads();
        for (int kk = 0; kk < 64; kk += 32) {
            short8 a = *(const short8*)&Es[w * 16 + r][kk + q * 8];
            short8 b[4];
            for (int ni = 0; ni < 4; ni++)
                b[ni] = *(const short8*)&Ts[ni * 16 + r][kk + q * 8];
            for (int ni = 0; ni < 4; ni++)
                acc[ni] = __builtin_amdgcn_mfma_f32_16x16x32_bf16(
                    a, b[ni], acc[ni], 0, 0, 0);
            accs = __builtin_amdgcn_mfma_f32_16x16x32_bf16(a, bones, accs, 0, 0, 0);
        }
        __syncthreads();
    }
    for (int reg = 0; reg < 4; reg++) {
        int grow = ti * 64 + w * 16 + q * 4 + reg;
        for (int ni = 0; ni < 4; ni++) {
            int gcol = ni * 16 + r;
            atomicAdd(&u[(((size_t)local * 4096) + grow) * 64 + gcol], acc[ni][reg]);
        }
        if (r == 0) atomicAdd(&s[(size_t)local * 4096 + grow], accs[reg]);
    }
}

// launcher-side wrapper passes per-bh tin base; to keep filter_p simple we
// bake the bh offset into tinT pointer via a trampoline kernel param instead.
__global__ __launch_bounds__(256) void filter_p2(
    const unsigned char* __restrict__ E, const ushort_t* __restrict__ tinT,
    float* __restrict__ u, float* __restrict__ s, int bh0) {
    __shared__ ushort_t Es[64][PAD];
    __shared__ ushort_t Ts[64][PAD];
    int bid = blockIdx.x;
    int local = bid >> 7;
    int rem = bid & 127;
    int ti = rem >> 1;
    int half = rem & 1;
    const unsigned char* Eg = E + (size_t)local * N_ * N_;
    const ushort_t* tin = tinT + (size_t)(bh0 + local) * 64 * N_;
    int tid = threadIdx.x, w = tid >> 6, lane = tid & 63, q = lane >> 4, r = lane & 15;
    float4v acc[4], accs;
    for (int e = 0; e < 4; e++) accs[e] = 0.f;
    for (int j = 0; j < 4; j++)
        for (int e = 0; e < 4; e++) acc[j][e] = 0.f;
    const short one_bf = (short)0x3F80;
    short8 bones = { one_bf, one_bf, one_bf, one_bf, one_bf, one_bf, one_bf, one_bf };

    int erow = tid >> 2, ejc = (tid & 3) * 16;

    int kbeg = half * (N_ / SPLIT), kend = kbeg + N_ / SPLIT;
    for (int k0 = kbeg; k0 < kend; k0 += 64) {
        uchar16v ev = *(const uchar16v*)&Eg[((size_t)(ti * 64 + erow)) * 4096 + k0 + ejc];
        short8 lo, hi;
        for (int e = 0; e < 8; e++) {
            lo[e] = (short)(((ushort_t)ev[e] << 4) + 0x3C00);
            hi[e] = (short)(((ushort_t)ev[e + 8] << 4) + 0x3C00);
        }
        *(short8*)&Es[erow][ejc] = lo;
        *(short8*)&Es[erow][ejc + 8] = hi;
        for (int it = 0; it < 2; it++) {
            int idx = tid + it * 256;
            int row = idx >> 3, jc = (idx & 7) * 8;
            *(short8*)&Ts[row][jc] = *(const short8*)&tin[(size_t)row * 4096 + k0 + jc];
        }
        __syncthreads();
        for (int kk = 0; kk < 64; kk += 32) {
            short8 a = *(const short8*)&Es[w * 16 + r][kk + q * 8];
            short8 b[4];
            for (int ni = 0; ni < 4; ni++)
                b[ni] = *(const short8*)&Ts[ni * 16 + r][kk + q * 8];
            for (int ni = 0; ni < 4; ni++)
                acc[ni] = __builtin_amdgcn_mfma_f32_16x16x32_bf16(
                    a, b[ni], acc[ni], 0, 0, 0);
            accs = __builtin_amdgcn_mfma_f32_16x16x32_bf16(a, bones, accs, 0, 0, 0);
        }
        __syncthreads();
    }
    for (int reg = 0; reg < 4; reg++) {
        int grow = ti * 64 + w * 16 + q * 4 + reg;
        for (int ni = 0; ni < 4; ni++) {
            int gcol = ni * 16 + r;
            atomicAdd(&u[(((size_t)local * 4096) + grow) * 64 + gcol], acc[ni][reg]);
        }
        if (r == 0) atomicAdd(&s[(size_t)local * 4096 + grow], accs[reg]);
    }
}

// ---------------- normalize: t = u/s ; y += ck t ; write transposed t -------
__global__ __launch_bounds__(256) void norm_kernel(
    const float* __restrict__ u, const float* __restrict__ s,
    float* __restrict__ y, ushort_t* __restrict__ toutT,
    const float* __restrict__ coeffs, int bh0, int kidx, int write_t) {
    int tid = threadIdx.x;
    int wave = tid >> 6, lane = tid & 63;
    size_t idx = (size_t)blockIdx.x * 4 + wave;   // local*4096 + n
    int local = (int)(idx >> 12), n = (int)(idx & 4095);
    int bh = bh0 + local;
    int h = bh & 7;
    float ck = coeffs[h * 4 + kidx];
    float t = u[idx * 64 + lane] / s[idx];
    y[((size_t)bh * 4096 + n) * 64 + lane] += ck * t;
    if (write_t)
        toutT[((size_t)bh * 64 + lane) * 4096 + n] = f2bf(t);
}

// ---------------- output projection: merged[8192,512] x Wo[512,256] ---------
__global__ __launch_bounds__(256) void out_gemm(
    const float* __restrict__ y, const ushort_t* __restrict__ WoT,
    float* __restrict__ out) {
    __shared__ ushort_t As[128][PAD];
    __shared__ ushort_t Bs[64][PAD];
    int bid = blockIdx.x;
    int tileN = bid & 3, tileM = bid >> 2;
    int tid = threadIdx.x, w = tid >> 6, lane = tid & 63, q = lane >> 4, r = lane & 15;
    int wr = w * 32;
    float4v acc[2][4];
    for (int i = 0; i < 2; i++)
        for (int j = 0; j < 4; j++)
            for (int e = 0; e < 4; e++) acc[i][j][e] = 0.f;

    for (int k0 = 0; k0 < 512; k0 += 64) {
        int h = k0 >> 6;
        for (int it = 0; it < 8; it++) {
            int idx = tid + it * 256;
            int row = idx >> 4, kc = (idx & 15) * 4;
            int grow = tileM * 128 + row;
            int b = grow >> 12, n = grow & 4095;
            const float4* src =
                (const float4*)&y[(((size_t)(b * H_ + h)) * N_ + n) * 64 + kc];
            float4 v = *src;
            ushort4v pv;
            pv[0] = f2bf(v.x); pv[1] = f2bf(v.y); pv[2] = f2bf(v.z); pv[3] = f2bf(v.w);
            *(ushort4v*)&As[row][kc] = pv;
        }
        for (int it = 0; it < 2; it++) {
            int idx = tid + it * 256;
            int row = idx >> 3, kc = (idx & 7) * 8;
            *(short8*)&Bs[row][kc] =
                *(const short8*)&WoT[(size_t)(tileN * 64 + row) * 512 + k0 + kc];
        }
        __syncthreads();
        for (int kk = 0; kk < 64; kk += 32) {
            short8 a[2], b[4];
            a[0] = *(const short8*)&As[wr + r][kk + q * 8];
            a[1] = *(const short8*)&As[wr + 16 + r][kk + q * 8];
            for (int ni = 0; ni < 4; ni++)
                b[ni] = *(const short8*)&Bs[ni * 16 + r][kk + q * 8];
            for (int mi = 0; mi < 2; mi++)
                for (int ni = 0; ni < 4; ni++)
                    acc[mi][ni] = __builtin_amdgcn_mfma_f32_16x16x32_bf16(
                        a[mi], b[ni], acc[mi][ni], 0, 0, 0);
        }
        __syncthreads();
    }
    for (int mi = 0; mi < 2; mi++)
        for (int reg = 0; reg < 4; reg++) {
            int grow = tileM * 128 + wr + mi * 16 + q * 4 + reg;
            for (int ni = 0; ni < 4; ni++) {
                int gcol = tileN * 64 + ni * 16 + r;
                out[(size_t)grow * 256 + gcol] = acc[mi][ni][reg];
            }
        }
}

// ---------------------------------------------------------------------------
extern "C" void kernel_launch(void* const* d_in, const int* in_sizes, int n_in,
                              void* d_out, int out_size, void* d_ws, size_t ws_size,
                              hipStream_t stream) {
    const float* x      = (const float*)d_in[0];
    const float* Wq     = (const float*)d_in[1];
    const float* Wk     = (const float*)d_in[2];
    const float* Wv     = (const float*)d_in[3];
    const float* Wo     = (const float*)d_in[4];
    const float* gamma  = (const float*)d_in[5];
    const float* beta   = (const float*)d_in[6];
    const float* coeffs = (const float*)d_in[7];
    float* out = (float*)d_out;

    char* ws = (char*)d_ws;
    size_t off = 0;
    auto alloc = [&](size_t bytes) -> void* {
        void* p = ws + off;
        off += (bytes + 255) & ~(size_t)255;
        return p;
    };
    ushort_t* xb    = (ushort_t*)alloc((size_t)B_ * N_ * D_ * 2);       // 4.2 MB
    ushort_t* WqkvT = (ushort_t*)alloc((size_t)3 * INNER_ * D_ * 2);
    ushort_t* WoT   = (ushort_t*)alloc((size_t)D_ * INNER_ * 2);
    ushort_t* Qb    = (ushort_t*)alloc((size_t)NBH * N_ * DH_ * 2);     // 8.4 MB
    ushort_t* Kb    = (ushort_t*)alloc((size_t)NBH * N_ * DH_ * 2);     // 8.4 MB
    ushort_t* Vb    = (ushort_t*)alloc((size_t)NBH * N_ * DH_ * 2);     // 8.4 MB
    ushort_t* t0T   = (ushort_t*)alloc((size_t)NBH * DH_ * N_ * 2);     // 8.4 MB
    ushort_t* t1T   = (ushort_t*)alloc((size_t)NBH * DH_ * N_ * 2);     // 8.4 MB
    float*    y     = (float*)alloc((size_t)NBH * N_ * DH_ * 4);        // 16.8 MB

    const size_t E1 = (size_t)N_ * N_;  // 16.78 MB per (b,h) in fp8
    // u/s sized for the group: allocate for max possible group then E after.
    int nbh_g = NBH;
    while (nbh_g > 1) {
        size_t need = off + (size_t)nbh_g * N_ * DH_ * 4 + (size_t)nbh_g * N_ * 4 + 512
                      + (size_t)nbh_g * E1;
        if (need <= ws_size) break;
        nbh_g >>= 1;
    }
    float* u = (float*)alloc((size_t)nbh_g * N_ * DH_ * 4);
    float* sbuf = (float*)alloc((size_t)nbh_g * N_ * 4);
    unsigned char* E = (unsigned char*)(ws + off);

    const int prep_total = B_ * N_ * D_ + 3 * INNER_ * D_ + D_ * INNER_;
    prep_kernel<<<(prep_total + 255) / 256, 256, 0, stream>>>(
        x, Wq, Wk, Wv, Wo, xb, WqkvT, WoT);
    proj_gemm<<<768, 256, 0, stream>>>(xb, WqkvT, Qb, Kb, Vb);
    ln_kernel<<<(NBH * N_) / 4, 256, 0, stream>>>(Vb, gamma, beta, coeffs, t0T, y);

    size_t u_bytes = (size_t)nbh_g * N_ * DH_ * 4;
    size_t s_bytes = (size_t)nbh_g * N_ * 4;
    int fgrid = nbh_g * 64 * SPLIT;
    int ngrid = (nbh_g * N_) / 4;

    for (int bh0 = 0; bh0 < NBH; bh0 += nbh_g) {
        s_kernel<<<nbh_g * 1024, 256, 0, stream>>>(Qb, Kb, E, bh0);
        // pass 1: t0 -> t1
        hipMemsetAsync(u, 0, u_bytes, stream);
        hipMemsetAsync(sbuf, 0, s_bytes, stream);
        filter_p2<<<fgrid, 256, 0, stream>>>(E, t0T, u, sbuf, bh0);
        norm_kernel<<<ngrid, 256, 0, stream>>>(u, sbuf, y, t1T, coeffs, bh0, 1, 1);
        // pass 2: t1 -> t0
        hipMemsetAsync(u, 0, u_bytes, stream);
        hipMemsetAsync(sbuf, 0, s_bytes, stream);
        filter_p2<<<fgrid, 256, 0, stream>>>(E, t1T, u, sbuf, bh0);
        norm_kernel<<<ngrid, 256, 0, stream>>>(u, sbuf, y, t0T, coeffs, bh0, 2, 1);
        // pass 3: t0 -> (y only)
        hipMemsetAsync(u, 0, u_bytes, stream);
        hipMemsetAsync(sbuf, 0, s_bytes, stream);
        filter_p2<<<fgrid, 256, 0, stream>>>(E, t0T, u, sbuf, bh0);
        norm_kernel<<<ngrid, 256, 0, stream>>>(u, sbuf, y, t1T, coeffs, bh0, 3, 0);
    }
    out_gemm<<<256, 256, 0, stream>>>(y, WoT, out);
}

// Round 5
// 604.418 us; speedup vs baseline: 7.5859x; 1.0477x over previous
//
#include <hip/hip_runtime.h>
#include <stdint.h>

#define B_ 2
#define N_ 4096
#define D_ 256
#define H_ 8
#define DH_ 64
#define INNER_ 512
#define NBH 16
#define PAD 72
#define FPAD 80
#define SPLIT 2

typedef unsigned short ushort_t;
typedef __attribute__((ext_vector_type(8))) short short8;
typedef __attribute__((ext_vector_type(4))) float float4v;
typedef __attribute__((ext_vector_type(4))) unsigned short ushort4v;
typedef __attribute__((ext_vector_type(4))) unsigned int uint4v;

__device__ __forceinline__ ushort_t f2bf(float f) {
    union { float f; unsigned int u; } v; v.f = f;
    unsigned int r = v.u + 0x7FFFu + ((v.u >> 16) & 1u);
    return (ushort_t)(r >> 16);
}
__device__ __forceinline__ float bf2f(ushort_t u) {
    union { unsigned int u; float f; } v; v.u = ((unsigned int)u) << 16;
    return v.f;
}
// fp8 e4m3 encode (RNE), positive normal values only (E = exp(..))
__device__ __forceinline__ unsigned char f2fp8(float f) {
    union { float f; unsigned int u; } v; v.f = f;
    unsigned int u = v.u + 0x7FFFFu + ((v.u >> 20) & 1u);
    return (unsigned char)(((u >> 20) & 0x7FF) - 960);  // ((e-120)<<3)|m
}
// full signed fp8 e4m3 encode with subnormal + clamp handling (for t values)
__device__ __forceinline__ unsigned char f2fp8s(float f) {
    union { float f; unsigned int u; } v; v.f = f;
    unsigned int s = (v.u >> 24) & 0x80u;
    v.u &= 0x7FFFFFFFu;
    float a = v.f;
    if (a >= 448.f) return (unsigned char)(s | 0x7E);
    if (a < 0.015625f) {
        int m = (int)(a * 512.f + 0.5f);
        return (unsigned char)(s | (unsigned)m);
    }
    unsigned int u = v.u + 0x7FFFFu + ((v.u >> 20) & 1u);
    return (unsigned char)(s | (((u >> 20) & 0x7FF) - 960));
}

// ---------------- prep: bf16 conversions + weight transposes ----------------
__global__ __launch_bounds__(256) void prep_kernel(
    const float* __restrict__ x, const float* __restrict__ Wq,
    const float* __restrict__ Wk, const float* __restrict__ Wv,
    const float* __restrict__ Wo,
    ushort_t* __restrict__ xb, ushort_t* __restrict__ WqkvT,
    ushort_t* __restrict__ WoT) {
    int idx = blockIdx.x * 256 + threadIdx.x;
    const int total_x = B_ * N_ * D_;
    const int total_wqkv = 3 * INNER_ * D_;
    const int total_wo = D_ * INNER_;
    if (idx < total_x) { xb[idx] = f2bf(x[idx]); return; }
    idx -= total_x;
    if (idx < total_wqkv) {
        int n = idx >> 8, k = idx & 255;
        int which = n >> 9, nn = n & 511;
        const float* W = (which == 0) ? Wq : ((which == 1) ? Wk : Wv);
        WqkvT[idx] = f2bf(W[k * INNER_ + nn]);
        return;
    }
    idx -= total_wqkv;
    if (idx < total_wo) {
        int c = idx >> 9, k = idx & 511;
        WoT[idx] = f2bf(Wo[k * D_ + c]);
    }
}

// ---------------- fused QKV projection GEMM: [8192,256] x [256,1536] --------
__global__ __launch_bounds__(256) void proj_gemm(
    const ushort_t* __restrict__ xb, const ushort_t* __restrict__ WqkvT,
    ushort_t* __restrict__ Qb, ushort_t* __restrict__ Kb,
    ushort_t* __restrict__ Vb) {
    __shared__ ushort_t As[128][PAD];
    __shared__ ushort_t Bs[128][PAD];
    int bid = blockIdx.x;
    int tileN = bid % 12, tileM = bid / 12;
    int tid = threadIdx.x;
    int w = tid >> 6, lane = tid & 63, q = lane >> 4, r = lane & 15;
    int wr = (w & 1) * 64, wc = (w >> 1) * 64;
    float4v acc[4][4];
    for (int i = 0; i < 4; i++)
        for (int j = 0; j < 4; j++)
            for (int e = 0; e < 4; e++) acc[i][j][e] = 0.f;

    for (int k0 = 0; k0 < 256; k0 += 64) {
        for (int it = 0; it < 4; it++) {
            int idx = tid + it * 256;
            int row = idx >> 3, kc = (idx & 7) * 8;
            *(short8*)&As[row][kc] =
                *(const short8*)&xb[(size_t)(tileM * 128 + row) * 256 + k0 + kc];
            *(short8*)&Bs[row][kc] =
                *(const short8*)&WqkvT[(size_t)(tileN * 128 + row) * 256 + k0 + kc];
        }
        __syncthreads();
        for (int kk = 0; kk < 64; kk += 32) {
            short8 a[4], b[4];
            for (int mi = 0; mi < 4; mi++)
                a[mi] = *(const short8*)&As[wr + mi * 16 + r][kk + q * 8];
            for (int ni = 0; ni < 4; ni++)
                b[ni] = *(const short8*)&Bs[wc + ni * 16 + r][kk + q * 8];
            for (int mi = 0; mi < 4; mi++)
                for (int ni = 0; ni < 4; ni++)
                    acc[mi][ni] = __builtin_amdgcn_mfma_f32_16x16x32_bf16(
                        a[mi], b[ni], acc[mi][ni], 0, 0, 0);
        }
        __syncthreads();
    }
    for (int mi = 0; mi < 4; mi++)
        for (int ni = 0; ni < 4; ni++)
            for (int reg = 0; reg < 4; reg++) {
                int grow = tileM * 128 + wr + mi * 16 + q * 4 + reg;
                int gcol = tileN * 128 + wc + ni * 16 + r;
                float v = acc[mi][ni][reg];
                int which = gcol >> 9, inner = gcol & 511;
                int h = inner >> 6, d = inner & 63;
                int b = grow >> 12, n = grow & 4095;
                size_t off = (((size_t)(b * H_ + h)) * N_ + n) * DH_ + d;
                if (which == 0) Qb[off] = f2bf(v);
                else if (which == 1) Kb[off] = f2bf(v);
                else Vb[off] = f2bf(v);
            }
}

// ---------------- per-head LayerNorm + y init + transposed fp8 t0 -----------
__global__ __launch_bounds__(256) void ln_kernel(
    const ushort_t* __restrict__ Vb, const float* __restrict__ gamma,
    const float* __restrict__ beta, const float* __restrict__ coeffs,
    unsigned char* __restrict__ t0T, float* __restrict__ y) {
    int tid = threadIdx.x;
    int wave = tid >> 6, lane = tid & 63;
    size_t row = (size_t)blockIdx.x * 4 + wave;   // bh*4096 + n
    int bh = (int)(row >> 12), n = (int)(row & 4095);
    int h = bh & 7;
    float v = bf2f(Vb[row * 64 + lane]);
    float s = v;
    for (int m = 32; m >= 1; m >>= 1) s += __shfl_xor(s, m, 64);
    float mu = s * (1.f / 64.f);
    float dv = v - mu;
    float s2 = dv * dv;
    for (int m = 32; m >= 1; m >>= 1) s2 += __shfl_xor(s2, m, 64);
    float var = s2 * (1.f / 64.f);
    float vln = dv * rsqrtf(var + 1e-5f) * gamma[lane] + beta[lane];
    float c0 = coeffs[h * 4 + 0];
    y[row * 64 + lane] = c0 * vln;
    t0T[((size_t)bh * 64 + lane) * 4096 + n] = f2fp8s(vln);
}

// ---------------- E = exp(Q K^T / 8), fp8 e4m3, per (b,h) in group ----------
__global__ __launch_bounds__(256) void s_kernel(
    const ushort_t* __restrict__ Qb, const ushort_t* __restrict__ Kb,
    unsigned char* __restrict__ E, int bh0) {
    __shared__ ushort_t As[128][PAD];
    __shared__ ushort_t Bs[128][PAD];
    int bid = blockIdx.x;
    int local = bid >> 10;
    int rem = bid & 1023;
    int ti = rem >> 5, tj = rem & 31;
    int bh = bh0 + local;
    const ushort_t* Q = Qb + (size_t)bh * N_ * 64;
    const ushort_t* K = Kb + (size_t)bh * N_ * 64;
    unsigned char* Eg = E + (size_t)local * N_ * N_;
    int tid = threadIdx.x, w = tid >> 6, lane = tid & 63, q = lane >> 4, r = lane & 15;
    int wr = (w & 1) * 64, wc = (w >> 1) * 64;
    float4v acc[4][4];
    for (int i = 0; i < 4; i++)
        for (int j = 0; j < 4; j++)
            for (int e = 0; e < 4; e++) acc[i][j][e] = 0.f;

    for (int it = 0; it < 4; it++) {
        int idx = tid + it * 256;
        int row = idx >> 3, kc = (idx & 7) * 8;
        *(short8*)&As[row][kc] = *(const short8*)&Q[(size_t)(ti * 128 + row) * 64 + kc];
        *(short8*)&Bs[row][kc] = *(const short8*)&K[(size_t)(tj * 128 + row) * 64 + kc];
    }
    __syncthreads();
    for (int kk = 0; kk < 64; kk += 32) {
        short8 a[4], b[4];
        for (int mi = 0; mi < 4; mi++)
            a[mi] = *(const short8*)&As[wr + mi * 16 + r][kk + q * 8];
        for (int ni = 0; ni < 4; ni++)
            b[ni] = *(const short8*)&Bs[wc + ni * 16 + r][kk + q * 8];
        for (int mi = 0; mi < 4; mi++)
            for (int ni = 0; ni < 4; ni++)
                acc[mi][ni] = __builtin_amdgcn_mfma_f32_16x16x32_bf16(
                    a[mi], b[ni], acc[mi][ni], 0, 0, 0);
    }
    for (int mi = 0; mi < 4; mi++)
        for (int ni = 0; ni < 4; ni++)
            for (int reg = 0; reg < 4; reg++) {
                int grow = ti * 128 + wr + mi * 16 + q * 4 + reg;
                int gcol = tj * 128 + wc + ni * 16 + r;
                Eg[(size_t)grow * 4096 + gcol] =
                    f2fp8(__expf(0.125f * acc[mi][ni][reg]));
            }
}

// ---------------- filter partial: u += E[:,chunk] t[chunk], s += rowsum -----
// all-fp8 MFMA, raw fp8 bytes staged in LDS (no decode), static control flow.
__global__ __launch_bounds__(256) void filter_p2(
    const unsigned char* __restrict__ E, const unsigned char* __restrict__ tinT,
    float* __restrict__ u, float* __restrict__ s, int bh0) {
    __shared__ unsigned char Es[64][FPAD];
    __shared__ unsigned char Ts[64][FPAD];
    int bid = blockIdx.x;
    int local = bid >> 7;              // bh within group (64 ti x SPLIT)
    int rem = bid & 127;
    int ti = rem >> 1;
    int half = rem & 1;
    const unsigned char* Eg = E + (size_t)local * N_ * N_;
    const unsigned char* tin = tinT + (size_t)(bh0 + local) * 64 * N_;
    int tid = threadIdx.x, w = tid >> 6, lane = tid & 63, q = lane >> 4, r = lane & 15;
    float4v acc[4], accs;
    for (int e = 0; e < 4; e++) accs[e] = 0.f;
    for (int j = 0; j < 4; j++)
        for (int e = 0; e < 4; e++) acc[j][e] = 0.f;
    const long bones = 0x3838383838383838L;  // 8x fp8(1.0)

    int srow = tid >> 2, scol = (tid & 3) * 16;   // 4 lanes per 64B row

    int kbeg = half * (N_ / SPLIT), kend = kbeg + N_ / SPLIT;
    for (int k0 = kbeg; k0 < kend; k0 += 64) {
        // stage raw fp8: one 16B load -> one 16B LDS store each, no element ops
        uint4v ev = *(const uint4v*)&Eg[((size_t)(ti * 64 + srow)) * 4096 + k0 + scol];
        uint4v tv = *(const uint4v*)&tin[(size_t)srow * 4096 + k0 + scol];
        *(uint4v*)&Es[srow][scol] = ev;
        *(uint4v*)&Ts[srow][scol] = tv;
        __syncthreads();
        {
            long a0 = *(const long*)&Es[w * 16 + r][0 + q * 8];
            long b0 = *(const long*)&Ts[0 * 16 + r][0 + q * 8];
            long b1 = *(const long*)&Ts[1 * 16 + r][0 + q * 8];
            long b2 = *(const long*)&Ts[2 * 16 + r][0 + q * 8];
            long b3 = *(const long*)&Ts[3 * 16 + r][0 + q * 8];
            acc[0] = __builtin_amdgcn_mfma_f32_16x16x32_fp8_fp8(a0, b0, acc[0], 0, 0, 0);
            acc[1] = __builtin_amdgcn_mfma_f32_16x16x32_fp8_fp8(a0, b1, acc[1], 0, 0, 0);
            acc[2] = __builtin_amdgcn_mfma_f32_16x16x32_fp8_fp8(a0, b2, acc[2], 0, 0, 0);
            acc[3] = __builtin_amdgcn_mfma_f32_16x16x32_fp8_fp8(a0, b3, acc[3], 0, 0, 0);
            accs   = __builtin_amdgcn_mfma_f32_16x16x32_fp8_fp8(a0, bones, accs, 0, 0, 0);
            long a1 = *(const long*)&Es[w * 16 + r][32 + q * 8];
            long c0 = *(const long*)&Ts[0 * 16 + r][32 + q * 8];
            long c1 = *(const long*)&Ts[1 * 16 + r][32 + q * 8];
            long c2 = *(const long*)&Ts[2 * 16 + r][32 + q * 8];
            long c3 = *(const long*)&Ts[3 * 16 + r][32 + q * 8];
            acc[0] = __builtin_amdgcn_mfma_f32_16x16x32_fp8_fp8(a1, c0, acc[0], 0, 0, 0);
            acc[1] = __builtin_amdgcn_mfma_f32_16x16x32_fp8_fp8(a1, c1, acc[1], 0, 0, 0);
            acc[2] = __builtin_amdgcn_mfma_f32_16x16x32_fp8_fp8(a1, c2, acc[2], 0, 0, 0);
            acc[3] = __builtin_amdgcn_mfma_f32_16x16x32_fp8_fp8(a1, c3, acc[3], 0, 0, 0);
            accs   = __builtin_amdgcn_mfma_f32_16x16x32_fp8_fp8(a1, bones, accs, 0, 0, 0);
        }
        __syncthreads();
    }
    for (int reg = 0; reg < 4; reg++) {
        int grow = ti * 64 + w * 16 + q * 4 + reg;
        for (int ni = 0; ni < 4; ni++) {
            int gcol = ni * 16 + r;
            atomicAdd(&u[(((size_t)local * 4096) + grow) * 64 + gcol], acc[ni][reg]);
        }
        if (r == 0) atomicAdd(&s[(size_t)local * 4096 + grow], accs[reg]);
    }
}

// ---------------- normalize: t = u/s ; y += ck t ; write transposed fp8 t ---
__global__ __launch_bounds__(256) void norm_kernel(
    const float* __restrict__ u, const float* __restrict__ s,
    float* __restrict__ y, unsigned char* __restrict__ toutT,
    const float* __restrict__ coeffs, int bh0, int kidx, int write_t) {
    int tid = threadIdx.x;
    int wave = tid >> 6, lane = tid & 63;
    size_t idx = (size_t)blockIdx.x * 4 + wave;   // local*4096 + n
    int local = (int)(idx >> 12), n = (int)(idx & 4095);
    int bh = bh0 + local;
    int h = bh & 7;
    float ck = coeffs[h * 4 + kidx];
    float t = u[idx * 64 + lane] / s[idx];
    y[((size_t)bh * 4096 + n) * 64 + lane] += ck * t;
    if (write_t)
        toutT[((size_t)bh * 64 + lane) * 4096 + n] = f2fp8s(t);
}

// ---------------- output projection: merged[8192,512] x Wo[512,256] ---------
__global__ __launch_bounds__(256) void out_gemm(
    const float* __restrict__ y, const ushort_t* __restrict__ WoT,
    float* __restrict__ out) {
    __shared__ ushort_t As[128][PAD];
    __shared__ ushort_t Bs[64][PAD];
    int bid = blockIdx.x;
    int tileN = bid & 3, tileM = bid >> 2;
    int tid = threadIdx.x, w = tid >> 6, lane = tid & 63, q = lane >> 4, r = lane & 15;
    int wr = w * 32;
    float4v acc[2][4];
    for (int i = 0; i < 2; i++)
        for (int j = 0; j < 4; j++)
            for (int e = 0; e < 4; e++) acc[i][j][e] = 0.f;

    for (int k0 = 0; k0 < 512; k0 += 64) {
        int h = k0 >> 6;
        for (int it = 0; it < 8; it++) {
            int idx = tid + it * 256;
            int row = idx >> 4, kc = (idx & 15) * 4;
            int grow = tileM * 128 + row;
            int b = grow >> 12, n = grow & 4095;
            const float4* src =
                (const float4*)&y[(((size_t)(b * H_ + h)) * N_ + n) * 64 + kc];
            float4 v = *src;
            ushort4v pv;
            pv[0] = f2bf(v.x); pv[1] = f2bf(v.y); pv[2] = f2bf(v.z); pv[3] = f2bf(v.w);
            *(ushort4v*)&As[row][kc] = pv;
        }
        for (int it = 0; it < 2; it++) {
            int idx = tid + it * 256;
            int row = idx >> 3, kc = (idx & 7) * 8;
            *(short8*)&Bs[row][kc] =
                *(const short8*)&WoT[(size_t)(tileN * 64 + row) * 512 + k0 + kc];
        }
        __syncthreads();
        for (int kk = 0; kk < 64; kk += 32) {
            short8 a[2], b[4];
            a[0] = *(const short8*)&As[wr + r][kk + q * 8];
            a[1] = *(const short8*)&As[wr + 16 + r][kk + q * 8];
            for (int ni = 0; ni < 4; ni++)
                b[ni] = *(const short8*)&Bs[ni * 16 + r][kk + q * 8];
            for (int mi = 0; mi < 2; mi++)
                for (int ni = 0; ni < 4; ni++)
                    acc[mi][ni] = __builtin_amdgcn_mfma_f32_16x16x32_bf16(
                        a[mi], b[ni], acc[mi][ni], 0, 0, 0);
        }
        __syncthreads();
    }
    for (int mi = 0; mi < 2; mi++)
        for (int reg = 0; reg < 4; reg++) {
            int grow = tileM * 128 + wr + mi * 16 + q * 4 + reg;
            for (int ni = 0; ni < 4; ni++) {
                int gcol = tileN * 64 + ni * 16 + r;
                out[(size_t)grow * 256 + gcol] = acc[mi][ni][reg];
            }
        }
}

// ---------------------------------------------------------------------------
extern "C" void kernel_launch(void* const* d_in, const int* in_sizes, int n_in,
                              void* d_out, int out_size, void* d_ws, size_t ws_size,
                              hipStream_t stream) {
    const float* x      = (const float*)d_in[0];
    const float* Wq     = (const float*)d_in[1];
    const float* Wk     = (const float*)d_in[2];
    const float* Wv     = (const float*)d_in[3];
    const float* Wo     = (const float*)d_in[4];
    const float* gamma  = (const float*)d_in[5];
    const float* beta   = (const float*)d_in[6];
    const float* coeffs = (const float*)d_in[7];
    float* out = (float*)d_out;

    char* ws = (char*)d_ws;
    size_t off = 0;
    auto alloc = [&](size_t bytes) -> void* {
        void* p = ws + off;
        off += (bytes + 255) & ~(size_t)255;
        return p;
    };
    ushort_t* xb    = (ushort_t*)alloc((size_t)B_ * N_ * D_ * 2);
    ushort_t* WqkvT = (ushort_t*)alloc((size_t)3 * INNER_ * D_ * 2);
    ushort_t* WoT   = (ushort_t*)alloc((size_t)D_ * INNER_ * 2);
    ushort_t* Qb    = (ushort_t*)alloc((size_t)NBH * N_ * DH_ * 2);
    ushort_t* Kb    = (ushort_t*)alloc((size_t)NBH * N_ * DH_ * 2);
    ushort_t* Vb    = (ushort_t*)alloc((size_t)NBH * N_ * DH_ * 2);
    unsigned char* t0T = (unsigned char*)alloc((size_t)NBH * DH_ * N_);
    unsigned char* t1T = (unsigned char*)alloc((size_t)NBH * DH_ * N_);
    float*    y     = (float*)alloc((size_t)NBH * N_ * DH_ * 4);

    const size_t E1 = (size_t)N_ * N_;  // 16.78 MB per (b,h) in fp8
    int nbh_g = NBH;
    while (nbh_g > 1) {
        size_t need = off + (size_t)nbh_g * N_ * DH_ * 4 + (size_t)nbh_g * N_ * 4 + 512
                      + (size_t)nbh_g * E1;
        if (need <= ws_size) break;
        nbh_g >>= 1;
    }
    float* u = (float*)alloc((size_t)nbh_g * N_ * DH_ * 4);
    float* sbuf = (float*)alloc((size_t)nbh_g * N_ * 4);
    unsigned char* E = (unsigned char*)(ws + off);

    const int prep_total = B_ * N_ * D_ + 3 * INNER_ * D_ + D_ * INNER_;
    prep_kernel<<<(prep_total + 255) / 256, 256, 0, stream>>>(
        x, Wq, Wk, Wv, Wo, xb, WqkvT, WoT);
    proj_gemm<<<768, 256, 0, stream>>>(xb, WqkvT, Qb, Kb, Vb);
    ln_kernel<<<(NBH * N_) / 4, 256, 0, stream>>>(Vb, gamma, beta, coeffs, t0T, y);

    size_t u_bytes = (size_t)nbh_g * N_ * DH_ * 4;
    size_t s_bytes = (size_t)nbh_g * N_ * 4;
    int fgrid = nbh_g * 64 * SPLIT;
    int ngrid = (nbh_g * N_) / 4;

    for (int bh0 = 0; bh0 < NBH; bh0 += nbh_g) {
        s_kernel<<<nbh_g * 1024, 256, 0, stream>>>(Qb, Kb, E, bh0);
        // pass 1: t0 -> t1
        hipMemsetAsync(u, 0, u_bytes, stream);
        hipMemsetAsync(sbuf, 0, s_bytes, stream);
        filter_p2<<<fgrid, 256, 0, stream>>>(E, t0T, u, sbuf, bh0);
        norm_kernel<<<ngrid, 256, 0, stream>>>(u, sbuf, y, t1T, coeffs, bh0, 1, 1);
        // pass 2: t1 -> t0
        hipMemsetAsync(u, 0, u_bytes, stream);
        hipMemsetAsync(sbuf, 0, s_bytes, stream);
        filter_p2<<<fgrid, 256, 0, stream>>>(E, t1T, u, sbuf, bh0);
        norm_kernel<<<ngrid, 256, 0, stream>>>(u, sbuf, y, t0T, coeffs, bh0, 2, 1);
        // pass 3: t0 -> (y only)
        hipMemsetAsync(u, 0, u_bytes, stream);
        hipMemsetAsync(sbuf, 0, s_bytes, stream);
        filter_p2<<<fgrid, 256, 0, stream>>>(E, t0T, u, sbuf, bh0);
        norm_kernel<<<ngrid, 256, 0, stream>>>(u, sbuf, y, t1T, coeffs, bh0, 3, 0);
    }
    out_gemm<<<256, 256, 0, stream>>>(y, WoT, out);
}

// Round 6
// 515.830 us; speedup vs baseline: 8.8887x; 1.1717x over previous
//
#include <hip/hip_runtime.h>
#include <stdint.h>

#define B_ 2
#define N_ 4096
#define D_ 256
#define H_ 8
#define DH_ 64
#define INNER_ 512
#define NBH 16
#define PAD 72
#define FPAD 80
#define SPLIT 2

typedef unsigned short ushort_t;
typedef __attribute__((ext_vector_type(8))) short short8;
typedef __attribute__((ext_vector_type(4))) float float4v;
typedef __attribute__((ext_vector_type(4))) unsigned short ushort4v;
typedef __attribute__((ext_vector_type(4))) unsigned int uint4v;

__device__ __forceinline__ ushort_t f2bf(float f) {
    union { float f; unsigned int u; } v; v.f = f;
    unsigned int r = v.u + 0x7FFFu + ((v.u >> 16) & 1u);
    return (ushort_t)(r >> 16);
}
__device__ __forceinline__ float bf2f(ushort_t u) {
    union { unsigned int u; float f; } v; v.u = ((unsigned int)u) << 16;
    return v.f;
}
// full signed fp8 e4m3 encode with subnormal + clamp handling (for t values)
__device__ __forceinline__ unsigned char f2fp8s(float f) {
    union { float f; unsigned int u; } v; v.f = f;
    unsigned int s = (v.u >> 24) & 0x80u;
    v.u &= 0x7FFFFFFFu;
    float a = v.f;
    if (a >= 448.f) return (unsigned char)(s | 0x7E);
    if (a < 0.015625f) {
        int m = (int)(a * 512.f + 0.5f);
        return (unsigned char)(s | (unsigned)m);
    }
    unsigned int u = v.u + 0x7FFFFu + ((v.u >> 20) & 1u);
    return (unsigned char)(s | (((u >> 20) & 0x7FF) - 960));
}

// ---------------- prep: bf16 conversions + weight transposes ----------------
__global__ __launch_bounds__(256) void prep_kernel(
    const float* __restrict__ x, const float* __restrict__ Wq,
    const float* __restrict__ Wk, const float* __restrict__ Wv,
    const float* __restrict__ Wo,
    ushort_t* __restrict__ xb, ushort_t* __restrict__ WqkvT,
    ushort_t* __restrict__ WoT) {
    int idx = blockIdx.x * 256 + threadIdx.x;
    const int total_x = B_ * N_ * D_;
    const int total_wqkv = 3 * INNER_ * D_;
    const int total_wo = D_ * INNER_;
    if (idx < total_x) { xb[idx] = f2bf(x[idx]); return; }
    idx -= total_x;
    if (idx < total_wqkv) {
        int n = idx >> 8, k = idx & 255;
        int which = n >> 9, nn = n & 511;
        const float* W = (which == 0) ? Wq : ((which == 1) ? Wk : Wv);
        WqkvT[idx] = f2bf(W[k * INNER_ + nn]);
        return;
    }
    idx -= total_wqkv;
    if (idx < total_wo) {
        int c = idx >> 9, k = idx & 511;
        WoT[idx] = f2bf(Wo[k * D_ + c]);
    }
}

// ---------------- fused QKV projection GEMM: [8192,256] x [256,1536] --------
__global__ __launch_bounds__(256) void proj_gemm(
    const ushort_t* __restrict__ xb, const ushort_t* __restrict__ WqkvT,
    ushort_t* __restrict__ Qb, ushort_t* __restrict__ Kb,
    ushort_t* __restrict__ Vb) {
    __shared__ ushort_t As[128][PAD];
    __shared__ ushort_t Bs[128][PAD];
    int bid = blockIdx.x;
    int tileN = bid % 12, tileM = bid / 12;
    int tid = threadIdx.x;
    int w = tid >> 6, lane = tid & 63, q = lane >> 4, r = lane & 15;
    int wr = (w & 1) * 64, wc = (w >> 1) * 64;
    float4v acc[4][4];
    for (int i = 0; i < 4; i++)
        for (int j = 0; j < 4; j++)
            for (int e = 0; e < 4; e++) acc[i][j][e] = 0.f;

    for (int k0 = 0; k0 < 256; k0 += 64) {
        for (int it = 0; it < 4; it++) {
            int idx = tid + it * 256;
            int row = idx >> 3, kc = (idx & 7) * 8;
            *(short8*)&As[row][kc] =
                *(const short8*)&xb[(size_t)(tileM * 128 + row) * 256 + k0 + kc];
            *(short8*)&Bs[row][kc] =
                *(const short8*)&WqkvT[(size_t)(tileN * 128 + row) * 256 + k0 + kc];
        }
        __syncthreads();
        for (int kk = 0; kk < 64; kk += 32) {
            short8 a[4], b[4];
            for (int mi = 0; mi < 4; mi++)
                a[mi] = *(const short8*)&As[wr + mi * 16 + r][kk + q * 8];
            for (int ni = 0; ni < 4; ni++)
                b[ni] = *(const short8*)&Bs[wc + ni * 16 + r][kk + q * 8];
            for (int mi = 0; mi < 4; mi++)
                for (int ni = 0; ni < 4; ni++)
                    acc[mi][ni] = __builtin_amdgcn_mfma_f32_16x16x32_bf16(
                        a[mi], b[ni], acc[mi][ni], 0, 0, 0);
        }
        __syncthreads();
    }
    for (int mi = 0; mi < 4; mi++)
        for (int ni = 0; ni < 4; ni++)
            for (int reg = 0; reg < 4; reg++) {
                int grow = tileM * 128 + wr + mi * 16 + q * 4 + reg;
                int gcol = tileN * 128 + wc + ni * 16 + r;
                float v = acc[mi][ni][reg];
                int which = gcol >> 9, inner = gcol & 511;
                int h = inner >> 6, d = inner & 63;
                int b = grow >> 12, n = grow & 4095;
                size_t off = (((size_t)(b * H_ + h)) * N_ + n) * DH_ + d;
                if (which == 0) Qb[off] = f2bf(v);
                else if (which == 1) Kb[off] = f2bf(v);
                else Vb[off] = f2bf(v);
            }
}

// ---------------- per-head LayerNorm + y init + transposed fp8 t0 -----------
__global__ __launch_bounds__(256) void ln_kernel(
    const ushort_t* __restrict__ Vb, const float* __restrict__ gamma,
    const float* __restrict__ beta, const float* __restrict__ coeffs,
    unsigned char* __restrict__ t0T, float* __restrict__ y) {
    int tid = threadIdx.x;
    int wave = tid >> 6, lane = tid & 63;
    size_t row = (size_t)blockIdx.x * 4 + wave;   // bh*4096 + n
    int bh = (int)(row >> 12), n = (int)(row & 4095);
    int h = bh & 7;
    float v = bf2f(Vb[row * 64 + lane]);
    float s = v;
    for (int m = 32; m >= 1; m >>= 1) s += __shfl_xor(s, m, 64);
    float mu = s * (1.f / 64.f);
    float dv = v - mu;
    float s2 = dv * dv;
    for (int m = 32; m >= 1; m >>= 1) s2 += __shfl_xor(s2, m, 64);
    float var = s2 * (1.f / 64.f);
    float vln = dv * rsqrtf(var + 1e-5f) * gamma[lane] + beta[lane];
    float c0 = coeffs[h * 4 + 0];
    y[row * 64 + lane] = c0 * vln;
    t0T[((size_t)bh * 64 + lane) * 4096 + n] = f2fp8s(vln);
}

// ---------------- E = exp(Q K^T / 8), fp8, coalesced dwordx4 stores ---------
// Swapped MFMA operands (A=K, B=Q) so per-lane regs run along j (E columns):
// pack 4 fp8 via v_cvt_pk_fp8_f32, bounce through LDS, store dwordx4.
__global__ __launch_bounds__(256) void s_kernel(
    const ushort_t* __restrict__ Qb, const ushort_t* __restrict__ Kb,
    unsigned char* __restrict__ E, int bh0) {
    __shared__ char smem[36864];
    ushort_t (*As)[PAD] = (ushort_t(*)[PAD])smem;            // Q tile 128x64
    ushort_t (*Bs)[PAD] = (ushort_t(*)[PAD])(smem + 18432);  // K tile 128x64
    unsigned int* E8 = (unsigned int*)smem;                   // 128 x 36 uints
    int bid = blockIdx.x;
    int local = bid >> 10;
    int rem = bid & 1023;
    int ti = rem >> 5, tj = rem & 31;
    int bh = bh0 + local;
    const ushort_t* Q = Qb + (size_t)bh * N_ * 64;
    const ushort_t* K = Kb + (size_t)bh * N_ * 64;
    unsigned char* Eg = E + (size_t)local * N_ * N_;
    int tid = threadIdx.x, w = tid >> 6, lane = tid & 63, q = lane >> 4, r = lane & 15;
    int wj = (w & 1) * 64, wi = (w >> 1) * 64;
    float4v acc[4][4];
    for (int i = 0; i < 4; i++)
        for (int j = 0; j < 4; j++)
            for (int e = 0; e < 4; e++) acc[i][j][e] = 0.f;

    for (int it = 0; it < 4; it++) {
        int idx = tid + it * 256;
        int row = idx >> 3, kc = (idx & 7) * 8;
        *(short8*)&As[row][kc] = *(const short8*)&Q[(size_t)(ti * 128 + row) * 64 + kc];
        *(short8*)&Bs[row][kc] = *(const short8*)&K[(size_t)(tj * 128 + row) * 64 + kc];
    }
    __syncthreads();
    for (int kk = 0; kk < 64; kk += 32) {
        short8 a[4], b[4];
        for (int mi = 0; mi < 4; mi++)             // A = K rows (j direction)
            a[mi] = *(const short8*)&Bs[wj + mi * 16 + r][kk + q * 8];
        for (int ni = 0; ni < 4; ni++)             // B = Q rows (i direction)
            b[ni] = *(const short8*)&As[wi + ni * 16 + r][kk + q * 8];
        for (int mi = 0; mi < 4; mi++)
            for (int ni = 0; ni < 4; ni++)
                acc[mi][ni] = __builtin_amdgcn_mfma_f32_16x16x32_bf16(
                    a[mi], b[ni], acc[mi][ni], 0, 0, 0);
    }
    __syncthreads();   // done with As/Bs; reuse as E8
    for (int mi = 0; mi < 4; mi++)
        for (int ni = 0; ni < 4; ni++) {
            float f0 = __expf(0.125f * acc[mi][ni][0]);
            float f1 = __expf(0.125f * acc[mi][ni][1]);
            float f2 = __expf(0.125f * acc[mi][ni][2]);
            float f3 = __expf(0.125f * acc[mi][ni][3]);
            int p = __builtin_amdgcn_cvt_pk_fp8_f32(f0, f1, 0, false);
            p = __builtin_amdgcn_cvt_pk_fp8_f32(f2, f3, p, true);
            int il = wi + ni * 16 + r;                       // E row i (local)
            int j4 = ((wj + mi * 16) >> 2) + q;              // E col / 4
            E8[il * 36 + j4] = (unsigned int)p;
        }
    __syncthreads();
    for (int it = 0; it < 4; it++) {
        int idx = tid + it * 256;                  // 0..1023
        int row = idx >> 3, c4 = (idx & 7) * 4;
        uint4v vv = *(const uint4v*)&E8[row * 36 + c4];
        *(uint4v*)&Eg[(size_t)(ti * 128 + row) * 4096 + tj * 128 + c4 * 4] = vv;
    }
}

// ---------------- filter partial: double-buffered fp8 MFMA ------------------
#define MFMA_STEP(EsX, TsX)                                                     \
    {                                                                           \
        long a0 = *(const long*)&EsX[w * 16 + r][q * 8];                        \
        long b0 = *(const long*)&TsX[r][q * 8];                                 \
        long b1 = *(const long*)&TsX[16 + r][q * 8];                            \
        long b2 = *(const long*)&TsX[32 + r][q * 8];                            \
        long b3 = *(const long*)&TsX[48 + r][q * 8];                            \
        acc[0] = __builtin_amdgcn_mfma_f32_16x16x32_fp8_fp8(a0, b0, acc[0], 0, 0, 0); \
        acc[1] = __builtin_amdgcn_mfma_f32_16x16x32_fp8_fp8(a0, b1, acc[1], 0, 0, 0); \
        acc[2] = __builtin_amdgcn_mfma_f32_16x16x32_fp8_fp8(a0, b2, acc[2], 0, 0, 0); \
        acc[3] = __builtin_amdgcn_mfma_f32_16x16x32_fp8_fp8(a0, b3, acc[3], 0, 0, 0); \
        accs = __builtin_amdgcn_mfma_f32_16x16x32_fp8_fp8(a0, bones, accs, 0, 0, 0);  \
        long a1 = *(const long*)&EsX[w * 16 + r][32 + q * 8];                   \
        long c0 = *(const long*)&TsX[r][32 + q * 8];                            \
        long c1 = *(const long*)&TsX[16 + r][32 + q * 8];                       \
        long c2 = *(const long*)&TsX[32 + r][32 + q * 8];                       \
        long c3 = *(const long*)&TsX[48 + r][32 + q * 8];                       \
        acc[0] = __builtin_amdgcn_mfma_f32_16x16x32_fp8_fp8(a1, c0, acc[0], 0, 0, 0); \
        acc[1] = __builtin_amdgcn_mfma_f32_16x16x32_fp8_fp8(a1, c1, acc[1], 0, 0, 0); \
        acc[2] = __builtin_amdgcn_mfma_f32_16x16x32_fp8_fp8(a1, c2, acc[2], 0, 0, 0); \
        acc[3] = __builtin_amdgcn_mfma_f32_16x16x32_fp8_fp8(a1, c3, acc[3], 0, 0, 0); \
        accs = __builtin_amdgcn_mfma_f32_16x16x32_fp8_fp8(a1, bones, accs, 0, 0, 0);  \
    }

__global__ __launch_bounds__(256) void filter_p2(
    const unsigned char* __restrict__ E, const unsigned char* __restrict__ tinT,
    float* __restrict__ u, float* __restrict__ sbuf, int bh0, int ng) {
    __shared__ unsigned char Es0[64][FPAD], Ts0[64][FPAD];
    __shared__ unsigned char Es1[64][FPAD], Ts1[64][FPAD];
    int bid = blockIdx.x;
    int local = bid >> 7;              // 64 ti x SPLIT(2) = 128 blocks per bh
    int rem = bid & 127;
    int ti = rem >> 1;
    int half = rem & 1;
    const unsigned char* Eg = E + (size_t)local * N_ * N_;
    const unsigned char* tin = tinT + (size_t)(bh0 + local) * 64 * N_;
    int tid = threadIdx.x, w = tid >> 6, lane = tid & 63, q = lane >> 4, r = lane & 15;
    float4v acc[4], accs;
    for (int e = 0; e < 4; e++) accs[e] = 0.f;
    for (int j = 0; j < 4; j++)
        for (int e = 0; e < 4; e++) acc[j][e] = 0.f;
    const long bones = 0x3838383838383838L;  // 8x fp8(1.0)

    int srow = tid >> 2, scol = (tid & 3) * 16;
    int kbeg = half * (N_ / SPLIT);
    const unsigned char* ep = Eg + (size_t)(ti * 64 + srow) * 4096 + kbeg + scol;
    const unsigned char* tp = tin + (size_t)srow * 4096 + kbeg + scol;

    uint4v e0 = *(const uint4v*)ep;
    uint4v t0v = *(const uint4v*)tp;
    *(uint4v*)&Es0[srow][scol] = e0;
    *(uint4v*)&Ts0[srow][scol] = t0v;

    const int KITER = (N_ / SPLIT) / 64;   // 32
    for (int it = 0; it < KITER; it += 2) {
        uint4v e1 = *(const uint4v*)(ep + (size_t)(it + 1) * 64);
        uint4v t1v = *(const uint4v*)(tp + (size_t)(it + 1) * 64);
        __syncthreads();                   // buf0 ready
        MFMA_STEP(Es0, Ts0);
        *(uint4v*)&Es1[srow][scol] = e1;
        *(uint4v*)&Ts1[srow][scol] = t1v;
        uint4v e2, t2v;
        if (it + 2 < KITER) {
            e2 = *(const uint4v*)(ep + (size_t)(it + 2) * 64);
            t2v = *(const uint4v*)(tp + (size_t)(it + 2) * 64);
        }
        __syncthreads();                   // buf1 ready
        MFMA_STEP(Es1, Ts1);
        if (it + 2 < KITER) {
            *(uint4v*)&Es0[srow][scol] = e2;
            *(uint4v*)&Ts0[srow][scol] = t2v;
        }
    }
    float* ub = u + ((size_t)(half * ng + local)) * N_ * 64;
    float* sb = sbuf + ((size_t)(half * ng + local)) * N_;
    for (int reg = 0; reg < 4; reg++) {
        int grow = ti * 64 + w * 16 + q * 4 + reg;
        for (int ni = 0; ni < 4; ni++) {
            int gcol = ni * 16 + r;
            ub[(size_t)grow * 64 + gcol] = acc[ni][reg];
        }
        if (r == 0) sb[grow] = accs[reg];
    }
}

// ---------------- normalize: t = (u0+u1)/(s0+s1) ; y += ck t ; fp8 t out ----
__global__ __launch_bounds__(256) void norm_kernel(
    const float* __restrict__ u, const float* __restrict__ sbuf,
    float* __restrict__ y, unsigned char* __restrict__ toutT,
    const float* __restrict__ coeffs, int bh0, int ng, int kidx, int write_t) {
    int tid = threadIdx.x;
    int wave = tid >> 6, lane = tid & 63;
    size_t idx = (size_t)blockIdx.x * 4 + wave;   // local*4096 + n
    int local = (int)(idx >> 12), n = (int)(idx & 4095);
    int bh = bh0 + local;
    int h = bh & 7;
    float ck = coeffs[h * 4 + kidx];
    float us = u[((size_t)local * N_ + n) * 64 + lane]
             + u[((size_t)(ng + local) * N_ + n) * 64 + lane];
    float ss = sbuf[(size_t)local * N_ + n] + sbuf[(size_t)(ng + local) * N_ + n];
    float t = us / ss;
    y[((size_t)bh * N_ + n) * 64 + lane] += ck * t;
    if (write_t)
        toutT[((size_t)bh * 64 + lane) * N_ + n] = f2fp8s(t);
}

// ---------------- output projection: merged[8192,512] x Wo[512,256] ---------
__global__ __launch_bounds__(256) void out_gemm(
    const float* __restrict__ y, const ushort_t* __restrict__ WoT,
    float* __restrict__ out) {
    __shared__ ushort_t As[128][PAD];
    __shared__ ushort_t Bs[64][PAD];
    int bid = blockIdx.x;
    int tileN = bid & 3, tileM = bid >> 2;
    int tid = threadIdx.x, w = tid >> 6, lane = tid & 63, q = lane >> 4, r = lane & 15;
    int wr = w * 32;
    float4v acc[2][4];
    for (int i = 0; i < 2; i++)
        for (int j = 0; j < 4; j++)
            for (int e = 0; e < 4; e++) acc[i][j][e] = 0.f;

    for (int k0 = 0; k0 < 512; k0 += 64) {
        int h = k0 >> 6;
        for (int it = 0; it < 8; it++) {
            int idx = tid + it * 256;
            int row = idx >> 4, kc = (idx & 15) * 4;
            int grow = tileM * 128 + row;
            int b = grow >> 12, n = grow & 4095;
            const float4* src =
                (const float4*)&y[(((size_t)(b * H_ + h)) * N_ + n) * 64 + kc];
            float4 v = *src;
            ushort4v pv;
            pv[0] = f2bf(v.x); pv[1] = f2bf(v.y); pv[2] = f2bf(v.z); pv[3] = f2bf(v.w);
            *(ushort4v*)&As[row][kc] = pv;
        }
        for (int it = 0; it < 2; it++) {
            int idx = tid + it * 256;
            int row = idx >> 3, kc = (idx & 7) * 8;
            *(short8*)&Bs[row][kc] =
                *(const short8*)&WoT[(size_t)(tileN * 64 + row) * 512 + k0 + kc];
        }
        __syncthreads();
        for (int kk = 0; kk < 64; kk += 32) {
            short8 a[2], b[4];
            a[0] = *(const short8*)&As[wr + r][kk + q * 8];
            a[1] = *(const short8*)&As[wr + 16 + r][kk + q * 8];
            for (int ni = 0; ni < 4; ni++)
                b[ni] = *(const short8*)&Bs[ni * 16 + r][kk + q * 8];
            for (int mi = 0; mi < 2; mi++)
                for (int ni = 0; ni < 4; ni++)
                    acc[mi][ni] = __builtin_amdgcn_mfma_f32_16x16x32_bf16(
                        a[mi], b[ni], acc[mi][ni], 0, 0, 0);
        }
        __syncthreads();
    }
    for (int mi = 0; mi < 2; mi++)
        for (int reg = 0; reg < 4; reg++) {
            int grow = tileM * 128 + wr + mi * 16 + q * 4 + reg;
            for (int ni = 0; ni < 4; ni++) {
                int gcol = tileN * 64 + ni * 16 + r;
                out[(size_t)grow * 256 + gcol] = acc[mi][ni][reg];
            }
        }
}

// ---------------------------------------------------------------------------
extern "C" void kernel_launch(void* const* d_in, const int* in_sizes, int n_in,
                              void* d_out, int out_size, void* d_ws, size_t ws_size,
                              hipStream_t stream) {
    const float* x      = (const float*)d_in[0];
    const float* Wq     = (const float*)d_in[1];
    const float* Wk     = (const float*)d_in[2];
    const float* Wv     = (const float*)d_in[3];
    const float* Wo     = (const float*)d_in[4];
    const float* gamma  = (const float*)d_in[5];
    const float* beta   = (const float*)d_in[6];
    const float* coeffs = (const float*)d_in[7];
    float* out = (float*)d_out;

    char* ws = (char*)d_ws;
    size_t off = 0;
    auto alloc = [&](size_t bytes) -> void* {
        void* p = ws + off;
        off += (bytes + 255) & ~(size_t)255;
        return p;
    };
    ushort_t* xb    = (ushort_t*)alloc((size_t)B_ * N_ * D_ * 2);
    ushort_t* WqkvT = (ushort_t*)alloc((size_t)3 * INNER_ * D_ * 2);
    ushort_t* WoT   = (ushort_t*)alloc((size_t)D_ * INNER_ * 2);
    ushort_t* Qb    = (ushort_t*)alloc((size_t)NBH * N_ * DH_ * 2);
    ushort_t* Kb    = (ushort_t*)alloc((size_t)NBH * N_ * DH_ * 2);
    unsigned char* t0T = (unsigned char*)alloc((size_t)NBH * DH_ * N_);
    unsigned char* t1T = (unsigned char*)alloc((size_t)NBH * DH_ * N_);
    float*    y     = (float*)alloc((size_t)NBH * N_ * DH_ * 4);

    const size_t E1 = (size_t)N_ * N_;  // 16.78 MB per (b,h) in fp8
    int nbh_g = 8;
    while (nbh_g > 1) {
        size_t need = off + (size_t)SPLIT * nbh_g * N_ * DH_ * 4
                      + (size_t)SPLIT * nbh_g * N_ * 4 + 1024
                      + (size_t)nbh_g * E1;
        if (need <= ws_size) break;
        nbh_g >>= 1;
    }
    float* u    = (float*)alloc((size_t)SPLIT * nbh_g * N_ * DH_ * 4);
    float* sbuf = (float*)alloc((size_t)SPLIT * nbh_g * N_ * 4);
    unsigned char* E = (unsigned char*)(ws + off);
    // V (bf16, 8.4 MB) aliased onto the E region: dead once ln_kernel has run,
    // before the first s_kernel write.
    ushort_t* Vb = (ushort_t*)E;

    const int prep_total = B_ * N_ * D_ + 3 * INNER_ * D_ + D_ * INNER_;
    prep_kernel<<<(prep_total + 255) / 256, 256, 0, stream>>>(
        x, Wq, Wk, Wv, Wo, xb, WqkvT, WoT);
    proj_gemm<<<768, 256, 0, stream>>>(xb, WqkvT, Qb, Kb, Vb);
    ln_kernel<<<(NBH * N_) / 4, 256, 0, stream>>>(Vb, gamma, beta, coeffs, t0T, y);

    int fgrid = nbh_g * 64 * SPLIT;
    int ngrid = (nbh_g * N_) / 4;

    for (int bh0 = 0; bh0 < NBH; bh0 += nbh_g) {
        s_kernel<<<nbh_g * 1024, 256, 0, stream>>>(Qb, Kb, E, bh0);
        filter_p2<<<fgrid, 256, 0, stream>>>(E, t0T, u, sbuf, bh0, nbh_g);
        norm_kernel<<<ngrid, 256, 0, stream>>>(u, sbuf, y, t1T, coeffs, bh0, nbh_g, 1, 1);
        filter_p2<<<fgrid, 256, 0, stream>>>(E, t1T, u, sbuf, bh0, nbh_g);
        norm_kernel<<<ngrid, 256, 0, stream>>>(u, sbuf, y, t0T, coeffs, bh0, nbh_g, 2, 1);
        filter_p2<<<fgrid, 256, 0, stream>>>(E, t0T, u, sbuf, bh0, nbh_g);
        norm_kernel<<<ngrid, 256, 0, stream>>>(u, sbuf, y, t1T, coeffs, bh0, nbh_g, 3, 0);
    }
    out_gemm<<<256, 256, 0, stream>>>(y, WoT, out);
}